// Round 13
// baseline (444.503 us; speedup 1.0000x reference)
//
#include <hip/hip_runtime.h>
#include <cfloat>

// E8 codebook quantize: per row of X[N][8]
//   neg mask, parity -> X_part = |X| with coord0 sign-fixed
//   scores = 2*dot - norm, argmax (first-max), vals/idx via sign-unflip + gather
//
// GOLDEN SCORING CHAIN (verified absmax=0 in R8/R9/R11/R12 — DO NOT CHANGE):
//   p_i = fl(x_i * g_i); q_i = fl(p_i + p_{i+4});
//   d = fl(fl(q0+q1)+fl(q2+q3)); s = fmaf(2,d,-n)  [== fl(fl(2d)-n), 2d exact]
//
// R13: two changes on the R12 skeleton (wave-pair P-split + readfirstlane):
//  1) inline-asm v_pk_mul_f32/v_pk_add_f32 for the golden chain. VOP3P
//     per-component rounding is IEEE-identical to the scalar ops, so bits
//     are unchanged. 19 -> 13 VALU insts/codeword. G stays in SGPR pairs
//     ("s" constraint) => R9 scalar s_load path preserved.
//  2) unroll 4 -> 8: halves the synchronous lgkmcnt stall frequency that
//     capped VALUBusy at ~65% in R9/R12.
//
// Output d_out (float*): vals [N*8] then real_idx [N] (int stored as float).
// allcombo/idx_map are int32-canonicalized on device (established R1-R3).

typedef float f32x2 __attribute__((ext_vector_type(2)));

__global__ __launch_bounds__(256, 8)
void e8_quant_kernel(const float* __restrict__ X,
                     const float* __restrict__ grid_part,   // [P*8] f32
                     const float* __restrict__ grid_norm,   // [P]   f32
                     const int*   __restrict__ allcombo,    // [128*P] int32
                     const int*   __restrict__ idx_map,     // [256] int32
                     float* __restrict__ out,               // [N*8 + N]
                     int N, int P)
{
    #pragma clang fp contract(off)

    __shared__ float s_best[2][64];
    __shared__ int   s_bidx[2][64];

    int lane   = threadIdx.x & 63;
    // wave-uniform by construction; readfirstlane makes the compiler see it
    int wave   = __builtin_amdgcn_readfirstlane(threadIdx.x >> 6);
    int pairid = wave >> 1;          // 0,1 : two row-groups per block (SGPR)
    int half   = wave & 1;           // 0: p=[0,P2), 1: p=[P2,P)   (SGPR)
    int row    = blockIdx.x * 128 + pairid * 64 + lane;   // N % 128 == 0

    const float4* xr = reinterpret_cast<const float4*>(X + (size_t)row * 8);
    float4 xa = xr[0];
    float4 xb = xr[1];
    float x[8] = { xa.x, xa.y, xa.z, xa.w, xb.x, xb.y, xb.z, xb.w };

    // neg mask + parity
    unsigned nm = 0u;
    #pragma unroll
    for (int c = 0; c < 8; ++c) nm |= (x[c] < 0.0f) ? (1u << c) : 0u;
    unsigned odd = __popc(nm) & 1u;

    // X_part = |x|, coord0 negated when parity odd (exact sign ops)
    float xp0 = fabsf(x[0]);
    xp0 = odd ? -xp0 : xp0;

    // packed X pairs (adjacent coords) for VOP3P
    f32x2 X01 = { xp0,         fabsf(x[1]) };
    f32x2 X23 = { fabsf(x[2]), fabsf(x[3]) };
    f32x2 X45 = { fabsf(x[4]), fabsf(x[5]) };
    f32x2 X67 = { fabsf(x[6]), fabsf(x[7]) };

    // this wave's codebook half — uniform SGPR bounds -> scalar s_load path
    int P2     = (P + 1) >> 1;
    int pstart = half ? P2 : 0;
    int pend   = half ? P  : P2;

    const float4* gp4 = reinterpret_cast<const float4*>(grid_part);
    float best = -FLT_MAX;
    int   bidx = 0;
    #pragma unroll 8
    for (int p = pstart; p < pend; ++p) {
        float4 ga = gp4[2 * p];
        float4 gb = gp4[2 * p + 1];
        float nrm = grid_norm[p];
        f32x2 G01 = { ga.x, ga.y };
        f32x2 G23 = { ga.z, ga.w };
        f32x2 G45 = { gb.x, gb.y };
        f32x2 G67 = { gb.z, gb.w };
        // golden chain, packed: per-component IEEE rounding identical to scalar
        f32x2 P01, P23, P45, P67, Q01, Q23;
        asm("v_pk_mul_f32 %0, %1, %2" : "=v"(P01) : "v"(X01), "s"(G01));
        asm("v_pk_mul_f32 %0, %1, %2" : "=v"(P23) : "v"(X23), "s"(G23));
        asm("v_pk_mul_f32 %0, %1, %2" : "=v"(P45) : "v"(X45), "s"(G45));
        asm("v_pk_mul_f32 %0, %1, %2" : "=v"(P67) : "v"(X67), "s"(G67));
        // stride-4 fold: (q0,q1) = P01+P45, (q2,q3) = P23+P67
        asm("v_pk_add_f32 %0, %1, %2" : "=v"(Q01) : "v"(P01), "v"(P45));
        asm("v_pk_add_f32 %0, %1, %2" : "=v"(Q23) : "v"(P23), "v"(P67));
        // adjacent merge (scalar, golden order)
        float t0 = Q01.x + Q01.y;
        float t1 = Q23.x + Q23.y;
        float d  = t0 + t1;
        // s = fl(2d - n): 2d exact, single rounding == fl(fl(2d)-n)
        float s  = fmaf(2.0f, d, -nrm);
        bool gt = (s > best);
        best = gt ? s : best;
        bidx = gt ? p : bidx;
    }

    // merge wave pair: upper half wins only on strict > (first-max exact:
    // upper-half indices are all larger, ties keep the lower half's winner)
    if (half == 1) {
        s_best[pairid][lane] = best;
        s_bidx[pairid][lane] = bidx;
    }
    __syncthreads();
    if (half == 1) return;
    {
        float bh = s_best[pairid][lane];
        int   ih = s_bidx[pairid][lane];
        if (bh > best) { best = bh; bidx = ih; }
    }

    // packed sign bits: bit c = neg[c] for c>=1, bit0 = neg0 ^ parity
    unsigned packed = (nm & 0xFEu) | ((nm ^ odd) & 1u);

    // vals = grid_part[best] * mask (exact sign flips)
    const float* g = grid_part + (size_t)bidx * 8;
    float v[8];
    #pragma unroll
    for (int c = 0; c < 8; ++c) {
        float gv = g[c];
        v[c] = ((packed >> c) & 1u) ? -gv : gv;
    }
    float4* orow = reinterpret_cast<float4*>(out + (size_t)row * 8);
    float4 o0 = { v[0], v[1], v[2], v[3] };
    float4 o1 = { v[4], v[5], v[6], v[7] };
    orow[0] = o0;
    orow[1] = o1;

    // real_idx = allcombo[idx_map[packed]][best]
    int crow = idx_map[packed];
    int idxv = allcombo[(size_t)crow * P + bidx];
    out[(size_t)N * 8 + row] = (float)idxv;
}

extern "C" void kernel_launch(void* const* d_in, const int* in_sizes, int n_in,
                              void* d_out, int out_size, void* d_ws, size_t ws_size,
                              hipStream_t stream) {
    const float* X        = (const float*)d_in[0];
    const float* gridpart = (const float*)d_in[1];
    const float* gridnorm = (const float*)d_in[2];
    // d_in[3] = int_map (2^c) — hardcoded as bit shifts
    const int*   allcombo = (const int*)d_in[4];
    const int*   idxmap   = (const int*)d_in[5];
    float* out = (float*)d_out;

    int N = in_sizes[0] / 8;
    int P = in_sizes[2];

    int block = 256;                    // 4 waves: 2 row-groups x 2 halves
    int grid  = (N + 127) / 128;        // 128 rows per block

    hipLaunchKernelGGL(e8_quant_kernel, dim3(grid), dim3(block), 0, stream,
                       X, gridpart, gridnorm, allcombo, idxmap, out, N, P);
}

// Round 15
// 303.290 us; speedup vs baseline: 1.4656x; 1.4656x over previous
//
#include <hip/hip_runtime.h>
#include <cfloat>

// E8 codebook quantize — MFMA-prefilter architecture (R15 = R14 + c==0 guard).
//
// GOLDEN SCORING CHAIN (verified absmax=0 in R8-R13 — DO NOT CHANGE):
//   p_i = fl(x_i*g_i); q_i = fl(p_i+p_{i+4});
//   d = fl(fl(q0+q1)+fl(q2+q3)); s = fmaf(2,d,-n)
//
// Pipeline:
//  k_setup : G_packed bf16 [NC][16] = [g|g] (g exact in bf16: half-ints <=3.5),
//            norms padded with +1e30, cnt[] zeroed.
//  k_sweep : per 32-row tile, mfma_f32_32x32x16_bf16 with A = [hi|lo] bf16
//            truncation-split of X_part (split exact; dropped residual
//            <= 2^-16|x|). s~ = fmaf(2,acc,-n). Sweep1: row maxima (v_max
//            only). Sweep2: deterministic recompute, emit cols with
//            s~ >= max - BAND to ws (atomic append, <=4 slots).
//  k_finish: exact golden chain on candidates, first-index tie-break;
//            cnt==0 or >4 -> full golden scan (prob ~0). Epilogue = R12.
// Correctness needs only BAND >= 2*max|s~ - s_golden| (~2.2e-3 worst case:
// 8 coords x 2^-16|x| x |g| x 2 + MFMA accum ~1e-5); BAND=8e-3 = 3.6x margin.
// Fallback to proven R9 kernel if ws/shape unsuitable.

#define NCMAX 3072
#define BAND  0.008f

typedef float f32x16 __attribute__((ext_vector_type(16)));
typedef short short8v __attribute__((ext_vector_type(8)));
union FragCast { unsigned int u[4]; short8v s; };

// ---------------- setup ----------------
__global__ __launch_bounds__(256)
void k_setup(const float* __restrict__ gp, const float* __restrict__ gn,
             unsigned int* __restrict__ wsG, float* __restrict__ wsN,
             int* __restrict__ cnt, int N, int P, int NC)
{
    int i = blockIdx.x * blockDim.x + threadIdx.x;
    if (i < NC) {
        unsigned int dw[4];
        #pragma unroll
        for (int j = 0; j < 4; ++j) {
            unsigned int lo = 0, hi = 0;
            if (i < P) {
                lo = __float_as_uint(gp[(size_t)i*8 + 2*j])   >> 16;   // exact bf16
                hi = __float_as_uint(gp[(size_t)i*8 + 2*j+1]) & 0xFFFF0000u;
            }
            dw[j] = hi | lo;
        }
        unsigned int* r = wsG + (size_t)i * 8;
        #pragma unroll
        for (int j = 0; j < 4; ++j) { r[j] = dw[j]; r[4+j] = dw[j]; }  // [g|g]
        wsN[i] = (i < P) ? gn[i] : 1.0e30f;                            // pad never wins
    }
    if (i < N) cnt[i] = 0;
}

// ---------------- MFMA double sweep ----------------
__global__ __launch_bounds__(256, 4)
void k_sweep(const float* __restrict__ X,
             const unsigned int* __restrict__ wsG, const float* __restrict__ wsN,
             int* __restrict__ cnt, int* __restrict__ cand,
             int NC)
{
    int lane = threadIdx.x & 63;
    int wave = __builtin_amdgcn_readfirstlane(threadIdx.x >> 6);
    int h    = lane >> 5;                       // K-half: 0=hi-split, 1=lo-split
    int rowbase = blockIdx.x * 128 + wave * 32;
    int arow = rowbase + (lane & 31);           // A row this lane supplies

    // load & sign-canonicalize (same as golden pre-step)
    const float4* xr = (const float4*)(X + (size_t)arow * 8);
    float4 xa = xr[0], xb = xr[1];
    float x[8] = {xa.x,xa.y,xa.z,xa.w,xb.x,xb.y,xb.z,xb.w};
    unsigned nm = 0;
    #pragma unroll
    for (int c = 0; c < 8; ++c) nm |= (x[c] < 0.0f) ? (1u<<c) : 0u;
    unsigned odd = __popc(nm) & 1u;
    float xp[8];
    #pragma unroll
    for (int c = 0; c < 8; ++c) xp[c] = fabsf(x[c]);
    if (odd) xp[0] = -xp[0];

    // bf16 truncation split: xp = hi + lo + r, split ops exact
    unsigned hd[4], ld[4];
    #pragma unroll
    for (int j = 0; j < 4; ++j) {
        unsigned u0 = __float_as_uint(xp[2*j]);
        unsigned u1 = __float_as_uint(xp[2*j+1]);
        hd[j] = (u1 & 0xFFFF0000u) | (u0 >> 16);
        float r0 = xp[2*j]   - __uint_as_float(u0 & 0xFFFF0000u);   // exact
        float r1 = xp[2*j+1] - __uint_as_float(u1 & 0xFFFF0000u);   // exact
        ld[j] = (__float_as_uint(r1) & 0xFFFF0000u) | (__float_as_uint(r0) >> 16);
    }
    FragCast af;
    #pragma unroll
    for (int j = 0; j < 4; ++j) af.u[j] = h ? ld[j] : hd[j];

    int NG   = NC >> 5;
    int coll = lane & 31;
    f32x16 zz = {};

    float bmax[16];
    #pragma unroll
    for (int j = 0; j < 16; ++j) bmax[j] = -FLT_MAX;

    // ---- sweep 1: per-row maxima ----
    #pragma unroll 2
    for (int g = 0; g < NG; ++g) {
        int col = (g << 5) + coll;
        uint4 bv = *(const uint4*)(wsG + (size_t)col*8 + h*4);
        FragCast bf; bf.u[0]=bv.x; bf.u[1]=bv.y; bf.u[2]=bv.z; bf.u[3]=bv.w;
        float nrm = wsN[col];
        f32x16 acc = __builtin_amdgcn_mfma_f32_32x32x16_bf16(af.s, bf.s, zz, 0,0,0);
        #pragma unroll
        for (int j = 0; j < 16; ++j) {
            float s = fmaf(2.0f, acc[j], -nrm);
            bmax[j] = fmaxf(bmax[j], s);
        }
    }
    // merge across the 32 col-lanes of each half (xor<=16 stays in-half)
    #pragma unroll
    for (int j = 0; j < 16; ++j) {
        float b = bmax[j];
        b = fmaxf(b, __shfl_xor(b, 1));
        b = fmaxf(b, __shfl_xor(b, 2));
        b = fmaxf(b, __shfl_xor(b, 4));
        b = fmaxf(b, __shfl_xor(b, 8));
        b = fmaxf(b, __shfl_xor(b, 16));
        bmax[j] = b - BAND;                      // threshold
    }
    // ---- sweep 2: deterministic recompute, emit band candidates ----
    #pragma unroll 2
    for (int g = 0; g < NG; ++g) {
        int col = (g << 5) + coll;
        uint4 bv = *(const uint4*)(wsG + (size_t)col*8 + h*4);
        FragCast bf; bf.u[0]=bv.x; bf.u[1]=bv.y; bf.u[2]=bv.z; bf.u[3]=bv.w;
        float nrm = wsN[col];
        f32x16 acc = __builtin_amdgcn_mfma_f32_32x32x16_bf16(af.s, bf.s, zz, 0,0,0);
        #pragma unroll
        for (int j = 0; j < 16; ++j) {
            float s = fmaf(2.0f, acc[j], -nrm);
            if (s >= bmax[j]) {
                int row  = rowbase + (j & 3) + 8*(j >> 2) + 4*h;   // verified C layout
                int slot = atomicAdd(&cnt[row], 1);
                if (slot < 4) cand[(size_t)row*4 + slot] = col;
            }
        }
    }
}

// golden score of one codeword (exact R8 chain)
__device__ __forceinline__ float golden(const float* xp, const float4& ga,
                                        const float4& gb, float nrm)
{
    float p0 = xp[0]*ga.x, p1 = xp[1]*ga.y, p2 = xp[2]*ga.z, p3 = xp[3]*ga.w;
    float p4 = xp[4]*gb.x, p5 = xp[5]*gb.y, p6 = xp[6]*gb.z, p7 = xp[7]*gb.w;
    float q0 = p0+p4, q1 = p1+p5, q2 = p2+p6, q3 = p3+p7;
    float t0 = q0+q1, t1 = q2+q3;
    float d  = t0+t1;
    return fmaf(2.0f, d, -nrm);
}

// ---------------- finisher ----------------
__global__ __launch_bounds__(256, 4)
void k_finish(const float* __restrict__ X,
              const float* __restrict__ gp, const float* __restrict__ gn,
              const int* __restrict__ allcombo, const int* __restrict__ idx_map,
              const int* __restrict__ cnt, const int* __restrict__ cand,
              float* __restrict__ out, int N, int P)
{
    #pragma clang fp contract(off)
    int row = blockIdx.x * blockDim.x + threadIdx.x;
    if (row >= N) return;

    const float4* xr = (const float4*)(X + (size_t)row * 8);
    float4 xa = xr[0], xb = xr[1];
    float x[8] = {xa.x,xa.y,xa.z,xa.w,xb.x,xb.y,xb.z,xb.w};
    unsigned nm = 0;
    #pragma unroll
    for (int c = 0; c < 8; ++c) nm |= (x[c] < 0.0f) ? (1u<<c) : 0u;
    unsigned odd = __popc(nm) & 1u;
    float xp[8];
    #pragma unroll
    for (int c = 0; c < 8; ++c) xp[c] = fabsf(x[c]);
    if (odd) xp[0] = -xp[0];

    int   c    = cnt[row];
    float best = -FLT_MAX;
    int   bidx = 0;
    if (c >= 1 && c <= 4) {
        bidx = 0x7FFFFFFF;
        #pragma unroll
        for (int t = 0; t < 4; ++t) {
            if (t < c) {
                int col = cand[(size_t)row*4 + t];
                const float4* g4 = (const float4*)(gp + (size_t)col*8);
                float s = golden(xp, g4[0], g4[1], gn[col]);
                if (s > best || (s == best && col < bidx)) { best = s; bidx = col; }
            }
        }
    } else {
        // c==0 (defensive) or >4 band-ties: full golden scan, ascending = first-max
        for (int p = 0; p < P; ++p) {
            const float4* g4 = (const float4*)(gp + (size_t)p*8);
            float s = golden(xp, g4[0], g4[1], gn[p]);
            if (s > best) { best = s; bidx = p; }
        }
    }

    unsigned packed = (nm & 0xFEu) | ((nm ^ odd) & 1u);
    const float* g = gp + (size_t)bidx * 8;
    float v[8];
    #pragma unroll
    for (int cc = 0; cc < 8; ++cc) {
        float gv = g[cc];
        v[cc] = ((packed >> cc) & 1u) ? -gv : gv;
    }
    float4* orow = (float4*)(out + (size_t)row * 8);
    float4 o0 = {v[0],v[1],v[2],v[3]};
    float4 o1 = {v[4],v[5],v[6],v[7]};
    orow[0] = o0; orow[1] = o1;

    int crow = idx_map[packed];
    out[(size_t)N*8 + row] = (float)allcombo[(size_t)crow * P + bidx];
}

// ---------------- proven fallback (R9) ----------------
__global__ __launch_bounds__(256, 4)
void e8_fallback(const float* __restrict__ X, const float* __restrict__ gp,
                 const float* __restrict__ gn, const int* __restrict__ allcombo,
                 const int* __restrict__ idx_map, float* __restrict__ out,
                 int N, int P)
{
    #pragma clang fp contract(off)
    int row = blockIdx.x * blockDim.x + threadIdx.x;
    if (row >= N) return;
    const float4* xr = (const float4*)(X + (size_t)row * 8);
    float4 xa = xr[0], xb = xr[1];
    float x[8] = {xa.x,xa.y,xa.z,xa.w,xb.x,xb.y,xb.z,xb.w};
    unsigned nm = 0;
    #pragma unroll
    for (int c = 0; c < 8; ++c) nm |= (x[c] < 0.0f) ? (1u<<c) : 0u;
    unsigned odd = __popc(nm) & 1u;
    float xp[8];
    #pragma unroll
    for (int c = 0; c < 8; ++c) xp[c] = fabsf(x[c]);
    if (odd) xp[0] = -xp[0];
    float best = -FLT_MAX; int bidx = 0;
    #pragma unroll 4
    for (int p = 0; p < P; ++p) {
        const float4* g4 = (const float4*)(gp + (size_t)p*8);
        float s = golden(xp, g4[0], g4[1], gn[p]);
        if (s > best) { best = s; bidx = p; }
    }
    unsigned packed = (nm & 0xFEu) | ((nm ^ odd) & 1u);
    const float* g = gp + (size_t)bidx * 8;
    float v[8];
    #pragma unroll
    for (int cc = 0; cc < 8; ++cc) {
        float gv = g[cc];
        v[cc] = ((packed >> cc) & 1u) ? -gv : gv;
    }
    float4* orow = (float4*)(out + (size_t)row * 8);
    float4 o0 = {v[0],v[1],v[2],v[3]};
    float4 o1 = {v[4],v[5],v[6],v[7]};
    orow[0] = o0; orow[1] = o1;
    int crow = idx_map[packed];
    out[(size_t)N*8 + row] = (float)allcombo[(size_t)crow * P + bidx];
}

extern "C" void kernel_launch(void* const* d_in, const int* in_sizes, int n_in,
                              void* d_out, int out_size, void* d_ws, size_t ws_size,
                              hipStream_t stream) {
    const float* X        = (const float*)d_in[0];
    const float* gridpart = (const float*)d_in[1];
    const float* gridnorm = (const float*)d_in[2];
    const int*   allcombo = (const int*)d_in[4];
    const int*   idxmap   = (const int*)d_in[5];
    float* out = (float*)d_out;

    int N  = in_sizes[0] / 8;
    int P  = in_sizes[2];
    int NC = (P + 31) & ~31;

    size_t offNrm  = (size_t)NCMAX * 32;        //  98304
    size_t offCnt  = 131072;
    size_t offCand = offCnt + (size_t)N * 4;
    size_t need    = offCand + (size_t)N * 16;

    if ((N % 128) == 0 && NC <= NCMAX && P >= 32 && ws_size >= need) {
        unsigned int* wsG = (unsigned int*)d_ws;
        float* wsN = (float*)((char*)d_ws + offNrm);
        int*   cnt = (int*)((char*)d_ws + offCnt);
        int*   cnd = (int*)((char*)d_ws + offCand);
        int setupGrid = ((N > NC ? N : NC) + 255) / 256;
        hipLaunchKernelGGL(k_setup, dim3(setupGrid), dim3(256), 0, stream,
                           gridpart, gridnorm, wsG, wsN, cnt, N, P, NC);
        hipLaunchKernelGGL(k_sweep, dim3(N / 128), dim3(256), 0, stream,
                           X, wsG, wsN, cnt, cnd, NC);
        hipLaunchKernelGGL(k_finish, dim3((N + 255) / 256), dim3(256), 0, stream,
                           X, gridpart, gridnorm, allcombo, idxmap, cnt, cnd,
                           out, N, P);
    } else {
        hipLaunchKernelGGL(e8_fallback, dim3((N + 255) / 256), dim3(256), 0, stream,
                           X, gridpart, gridnorm, allcombo, idxmap, out, N, P);
    }
}